// Round 1
// baseline (409.159 us; speedup 1.0000x reference)
//
#include <hip/hip_runtime.h>

#define WAVLEN  160000
#define NFRAMES 626
#define NFFT    1024
#define HOP     256
#define NSTFT   513
#define NMELS   80

// One 1024-pt FFT frame per 256-thread block.
// Twiddle tables twr/twi are row k=1 of the provided rfft matrices:
//   twr[n] = cos(-2*pi*n/1024), twi[n] = sin(-2*pi*n/1024), n = 0..1023.
__global__ __launch_bounds__(256) void melspec_fft_kernel(
    const float* __restrict__ wav,     // [B][160000]
    const float* __restrict__ window,  // [1024]
    const float* __restrict__ fb,      // [513][80]
    const float* __restrict__ twr,     // [1024]
    const float* __restrict__ twi,     // [1024]
    float* __restrict__ out)           // [B][80][626]
{
    __shared__ float sre[NFFT];
    __shared__ float sim[NFFT];
    __shared__ float smag[NSTFT];
    __shared__ float pmel[3][NMELS];

    const int tid   = threadIdx.x;
    const int frame = blockIdx.x % NFRAMES;
    const int b     = blockIdx.x / NFRAMES;
    const float* wb = wav + (size_t)b * WAVLEN;
    const int base  = frame * HOP - (NFFT / 2);   // reflect-pad origin

    // ---- load + window + bit-reverse scatter into LDS ----
    #pragma unroll
    for (int it = 0; it < 4; ++it) {
        int i = tid + it * 256;
        int j = base + i;
        j = (j < 0) ? (-j) : j;                       // left reflect
        j = (j >= WAVLEN) ? (2 * WAVLEN - 2 - j) : j; // right reflect
        float v = wb[j] * window[i];
        int r = (int)(__brev((unsigned)i) >> 22);     // 10-bit reverse
        sre[r] = v;
        sim[r] = 0.0f;
    }
    __syncthreads();

    // ---- 10 radix-2 DIT stages ----
    #pragma unroll
    for (int s = 1; s <= 10; ++s) {
        const int half = 1 << (s - 1);
        const int tw_shift = 10 - s;
        #pragma unroll
        for (int it = 0; it < 2; ++it) {
            int t  = tid + it * 256;                  // butterfly id 0..511
            int j  = t & (half - 1);
            int i1 = ((t >> (s - 1)) << s) + j;
            int i2 = i1 + half;
            float wr = twr[j << tw_shift];
            float wi = twi[j << tw_shift];
            float ur = sre[i1], ui = sim[i1];
            float vr = sre[i2], vi = sim[i2];
            float tr = fmaf(vr, wr, -vi * wi);
            float ti = fmaf(vr, wi,  vi * wr);
            sre[i1] = ur + tr;
            sim[i1] = ui + ti;
            sre[i2] = ur - tr;
            sim[i2] = ui - ti;
        }
        __syncthreads();
    }

    // ---- magnitude, k = 0..512 ----
    for (int k = tid; k < NSTFT; k += 256) {
        float re = sre[k], im = sim[k];
        smag[k] = sqrtf(fmaf(re, re, im * im));
    }
    __syncthreads();

    // ---- mel projection: 3 k-segments x 80 mels (240 active lanes) ----
    {
        int m   = tid % NMELS;
        int seg = tid / NMELS;
        if (seg < 3) {
            int k0 = seg * 171;
            int k1 = (seg == 2) ? NSTFT : (k0 + 171);
            float acc = 0.0f;
            for (int k = k0; k < k1; ++k)
                acc = fmaf(smag[k], fb[k * NMELS + m], acc);
            pmel[seg][m] = acc;
        }
    }
    __syncthreads();

    if (tid < NMELS) {
        float v = pmel[0][tid] + pmel[1][tid] + pmel[2][tid];
        out[((size_t)b * NMELS + tid) * NFRAMES + frame] = v;
    }
}

extern "C" void kernel_launch(void* const* d_in, const int* in_sizes, int n_in,
                              void* d_out, int out_size, void* d_ws, size_t ws_size,
                              hipStream_t stream) {
    const float* wav    = (const float*)d_in[0];
    const float* window = (const float*)d_in[1];
    const float* fb     = (const float*)d_in[2];
    const float* rfr    = (const float*)d_in[3];
    const float* rfi    = (const float*)d_in[4];
    float* out = (float*)d_out;

    int B = in_sizes[0] / WAVLEN;          // 32
    dim3 grid(B * NFRAMES);                // 20032 blocks
    melspec_fft_kernel<<<grid, 256, 0, stream>>>(
        wav, window, fb, rfr + NFFT, rfi + NFFT, out);
}

// Round 5
// 187.903 us; speedup vs baseline: 2.1775x; 2.1775x over previous
//
#include <hip/hip_runtime.h>

#define WAVLEN  160000
#define NFRAMES 626
#define NFFT    1024
#define HOP     256
#define NSTFT   513
#define NMELS   80
#define FBLKS   157               // ceil(626/4) frame-blocks per batch
#define PAD(i)  ((i) + ((i) >> 3))
#define BUFSZ   576               // PAD(511)=574 -> round up

__device__ __forceinline__ float2 cadd(float2 a, float2 b){ return make_float2(a.x+b.x, a.y+b.y); }
__device__ __forceinline__ float2 csub(float2 a, float2 b){ return make_float2(a.x-b.x, a.y-b.y); }
__device__ __forceinline__ float2 cmul(float2 a, float2 b){
    return make_float2(fmaf(a.x, b.x, -a.y*b.y), fmaf(a.x, b.y, a.y*b.x));
}
__device__ __forceinline__ float2 mulnegi(float2 a){ return make_float2(a.y, -a.x); } // a * (-i)

__device__ __forceinline__ void fft4(float2& a0, float2& a1, float2& a2, float2& a3) {
    float2 t0 = cadd(a0, a2), t1 = csub(a0, a2);
    float2 t2 = cadd(a1, a3), t3 = csub(a1, a3);
    a0 = cadd(t0, t2); a2 = csub(t0, t2);
    float2 nt3 = mulnegi(t3);
    a1 = cadd(t1, nt3); a3 = csub(t1, nt3);
}

// 8-point DFT, natural in / natural out, no external twiddles.
__device__ __forceinline__ void fft8(float2 v[8]) {
    float2 e0=v[0], e1=v[2], e2=v[4], e3=v[6];
    float2 o0=v[1], o1=v[3], o2=v[5], o3=v[7];
    fft4(e0,e1,e2,e3);
    fft4(o0,o1,o2,o3);
    const float C = 0.70710678118654752f;
    float2 w1o = make_float2(C*(o1.x + o1.y), C*(o1.y - o1.x));   // o1 * c(1-i)
    float2 w2o = mulnegi(o2);                                     // o2 * (-i)
    float2 w3o = make_float2(C*(o3.y - o3.x), -C*(o3.x + o3.y));  // o3 * c(-1-i)
    v[0] = cadd(e0, o0);  v[4] = csub(e0, o0);
    v[1] = cadd(e1, w1o); v[5] = csub(e1, w1o);
    v[2] = cadd(e2, w2o); v[6] = csub(e2, w2o);
    v[3] = cadd(e3, w3o); v[7] = csub(e3, w3o);
}

// Prep: find [kmin, kmax] of nonzero rows for each mel column. ~1 us, 1 block.
__global__ __launch_bounds__(640) void mel_range_kernel(const float* __restrict__ fb,
                                                        int2* __restrict__ rng) {
    __shared__ int kmin[NMELS], kmax[NMELS];
    int tid = threadIdx.x;
    if (tid < NMELS) { kmin[tid] = NSTFT; kmax[tid] = -1; }
    __syncthreads();
    int m = tid >> 3, seg = tid & 7;
    if (m < NMELS) {
        int k0 = seg * 65, k1 = min(NSTFT, k0 + 65);
        int lmin = NSTFT, lmax = -1;
        for (int k = k0; k < k1; ++k)
            if (fb[k * NMELS + m] > 0.f) { lmin = min(lmin, k); lmax = max(lmax, k); }
        if (lmax >= 0) { atomicMin(&kmin[m], lmin); atomicMax(&kmax[m], lmax); }
    }
    __syncthreads();
    if (tid < NMELS) rng[tid] = make_int2(kmin[tid], kmax[tid] + 1);
}

// One wave (64 lanes) per frame; 4 frames per 256-thread block.
// Packed-real 512-pt radix-8 Stockham FFT, 3 stages, stage 1 fused with load.
__global__ __launch_bounds__(256) void melspec_kernel(
    const float* __restrict__ wav,     // [B][160000]
    const float* __restrict__ window,  // [1024]
    const float* __restrict__ fb,      // [513][80]
    const float* __restrict__ twr,     // cos(-2pi n/1024), n=0..1023
    const float* __restrict__ twi,     // sin(-2pi n/1024)
    const int2* __restrict__ rng,      // [80] nonzero k-ranges (may be null)
    float* __restrict__ out)           // [B][80][626]
{
    __shared__ float2 buf[4][2][BUFSZ];   // per-wave ping/pong (36864 B)

    const int tid  = threadIdx.x;
    const int lane = tid & 63;
    const int w    = tid >> 6;
    const int b    = blockIdx.x / FBLKS;
    const int fblk = blockIdx.x % FBLKS;
    const int frame = fblk * 4 + w;
    const bool active = frame < NFRAMES;

    float2* A = buf[w][0];
    float2* B = buf[w][1];
    float2 v[8];

    // ---- load + window + fused stage 1 (Ns=1, no twiddles) ----
    if (active) {
        const float* wb = wav + (size_t)b * WAVLEN;
        const int base = frame * HOP - 512;
        if (base >= 0 && base + NFFT <= WAVLEN) {
            #pragma unroll
            for (int r = 0; r < 8; ++r) {
                int n = lane + 64 * r;
                float2 s  = *(const float2*)(wb + base + 2 * n);
                float2 wn = *(const float2*)(window + 2 * n);
                v[r] = make_float2(s.x * wn.x, s.y * wn.y);
            }
        } else {
            #pragma unroll
            for (int r = 0; r < 8; ++r) {
                int n = lane + 64 * r;
                int g0 = base + 2 * n, g1 = g0 + 1;
                g0 = g0 < 0 ? -g0 : (g0 >= WAVLEN ? 2 * WAVLEN - 2 - g0 : g0);
                g1 = g1 < 0 ? -g1 : (g1 >= WAVLEN ? 2 * WAVLEN - 2 - g1 : g1);
                v[r] = make_float2(wb[g0] * window[2 * n], wb[g1] * window[2 * n + 1]);
            }
        }
        fft8(v);
        #pragma unroll
        for (int r = 0; r < 8; ++r) B[PAD(8 * lane + r)] = v[r];
    }
    __syncthreads();

    // ---- stage 2: Ns=8 ----
    if (active) {
        #pragma unroll
        for (int r = 0; r < 8; ++r) v[r] = B[PAD(lane + 64 * r)];
        const int jm = lane & 7;
        #pragma unroll
        for (int r = 1; r < 8; ++r) {
            int idx = 16 * r * jm;             // r*(j%8)/64 in 1/1024 units
            v[r] = cmul(v[r], make_float2(twr[idx], twi[idx]));
        }
        fft8(v);
        const int idxD = (lane >> 3) * 64 + jm;
        #pragma unroll
        for (int r = 0; r < 8; ++r) A[PAD(idxD + 8 * r)] = v[r];
    }
    __syncthreads();

    // ---- stage 3: Ns=64 ----
    if (active) {
        #pragma unroll
        for (int r = 0; r < 8; ++r) v[r] = A[PAD(lane + 64 * r)];
        #pragma unroll
        for (int r = 1; r < 8; ++r) {
            int idx = 2 * r * lane;            // r*(j%64)/512 in 1/1024 units
            v[r] = cmul(v[r], make_float2(twr[idx], twi[idx]));
        }
        fft8(v);
        #pragma unroll
        for (int r = 0; r < 8; ++r) B[PAD(lane + 64 * r)] = v[r];
    }
    __syncthreads();

    // ---- Hermitian unpack + magnitude: smag[k], k=0..512, into A ----
    float* smag = (float*)A;
    if (active) {
        #pragma unroll
        for (int r = 0; r < 8; ++r) {
            int k = lane + 64 * r;
            if (k == 0) {
                float2 z0 = B[PAD(0)];
                smag[0]   = fabsf(z0.x + z0.y);
                smag[512] = fabsf(z0.x - z0.y);
            } else {
                float2 zk = B[PAD(k)];
                float2 zm = B[PAD(512 - k)];
                float xer = 0.5f * (zk.x + zm.x), xei = 0.5f * (zk.y - zm.y);
                float xod = 0.5f * (zk.y + zm.y), xoi = 0.5f * (zm.x - zk.x);
                float wr = twr[k], wi = twi[k];
                float xr = xer + fmaf(xod, wr, -xoi * wi);
                float xi = xei + fmaf(xod, wi,  xoi * wr);
                smag[k] = sqrtf(fmaf(xr, xr, xi * xi));
            }
        }
    }
    __syncthreads();

    // ---- sparse mel projection: lane m and (lane<16) m+64 ----
    float* pmel = (float*)B;
    if (active) {
        int m = lane;
        int2 rr = rng ? rng[m] : make_int2(0, NSTFT);
        float acc = 0.f;
        for (int k = rr.x; k < rr.y; ++k)
            acc = fmaf(smag[k], fb[k * NMELS + m], acc);
        pmel[m] = acc;
        if (lane < 16) {
            m = lane + 64;
            rr = rng ? rng[m] : make_int2(0, NSTFT);
            acc = 0.f;
            for (int k = rr.x; k < rr.y; ++k)
                acc = fmaf(smag[k], fb[k * NMELS + m], acc);
            pmel[m] = acc;
        }
    }
    __syncthreads();

    // ---- coalesced output: thread pair writes float2 along frame dim ----
    if (tid < 160) {
        int m = tid >> 1, h = tid & 1;
        int f0 = fblk * 4 + 2 * h;
        if (f0 < NFRAMES) {
            float2 o;
            o.x = ((float*)buf[2 * h][1])[m];
            o.y = ((float*)buf[2 * h + 1][1])[m];
            *(float2*)(out + ((size_t)b * NMELS + m) * NFRAMES + f0) = o;
        }
    }
}

extern "C" void kernel_launch(void* const* d_in, const int* in_sizes, int n_in,
                              void* d_out, int out_size, void* d_ws, size_t ws_size,
                              hipStream_t stream) {
    const float* wav    = (const float*)d_in[0];
    const float* window = (const float*)d_in[1];
    const float* fb     = (const float*)d_in[2];
    const float* rfr    = (const float*)d_in[3];
    const float* rfi    = (const float*)d_in[4];
    float* out = (float*)d_out;

    int2* rng = nullptr;
    if (ws_size >= NMELS * sizeof(int2)) {
        rng = (int2*)d_ws;
        mel_range_kernel<<<1, 640, 0, stream>>>(fb, rng);
    }

    int B = in_sizes[0] / WAVLEN;            // 32
    melspec_kernel<<<dim3(B * FBLKS), 256, 0, stream>>>(
        wav, window, fb, rfr + NFFT, rfi + NFFT, rng, out);
}

// Round 6
// 160.060 us; speedup vs baseline: 2.5563x; 1.1740x over previous
//
#include <hip/hip_runtime.h>

#define WAVLEN  160000
#define NFRAMES 626
#define NFFT    1024
#define HOP     256
#define NSTFT   513
#define NMELS   80
#define FBLKS   157               // ceil(626/4) frame-blocks per batch
#define PAD(i)  ((i) + ((i) >> 3))
#define BUFSZ   576               // PAD(511)=574 -> round up
#define SMAGSZ  516

__device__ __forceinline__ float2 cadd(float2 a, float2 b){ return make_float2(a.x+b.x, a.y+b.y); }
__device__ __forceinline__ float2 csub(float2 a, float2 b){ return make_float2(a.x-b.x, a.y-b.y); }
__device__ __forceinline__ float2 cmul(float2 a, float2 b){
    return make_float2(fmaf(a.x, b.x, -a.y*b.y), fmaf(a.x, b.y, a.y*b.x));
}
__device__ __forceinline__ float2 mulnegi(float2 a){ return make_float2(a.y, -a.x); } // a * (-i)

__device__ __forceinline__ void fft4(float2& a0, float2& a1, float2& a2, float2& a3) {
    float2 t0 = cadd(a0, a2), t1 = csub(a0, a2);
    float2 t2 = cadd(a1, a3), t3 = csub(a1, a3);
    a0 = cadd(t0, t2); a2 = csub(t0, t2);
    float2 nt3 = mulnegi(t3);
    a1 = cadd(t1, nt3); a3 = csub(t1, nt3);
}

// 8-point DFT, natural in / natural out, no external twiddles.
__device__ __forceinline__ void fft8(float2 v[8]) {
    float2 e0=v[0], e1=v[2], e2=v[4], e3=v[6];
    float2 o0=v[1], o1=v[3], o2=v[5], o3=v[7];
    fft4(e0,e1,e2,e3);
    fft4(o0,o1,o2,o3);
    const float C = 0.70710678118654752f;
    float2 w1o = make_float2(C*(o1.x + o1.y), C*(o1.y - o1.x));   // o1 * c(1-i)
    float2 w2o = mulnegi(o2);                                     // o2 * (-i)
    float2 w3o = make_float2(C*(o3.y - o3.x), -C*(o3.x + o3.y));  // o3 * c(-1-i)
    v[0] = cadd(e0, o0);  v[4] = csub(e0, o0);
    v[1] = cadd(e1, w1o); v[5] = csub(e1, w1o);
    v[2] = cadd(e2, w2o); v[6] = csub(e2, w2o);
    v[3] = cadd(e3, w3o); v[7] = csub(e3, w3o);
}

// Analytic Slaney mel-band support [klo, khi) with +/-1-bin margin.
// Extra bins read fb==0, so a conservative range is unconditionally correct.
__device__ __forceinline__ int2 mel_range(int m) {
    const float LOGSTEP = 0.06875177742094912f;   // ln(6.4)/27
    const float MSTEP   = 0.55858524f;            // (15 + ln(8)/LOGSTEP)/81
    float mlo = (float)m * MSTEP;
    float mhi = (float)(m + 2) * MSTEP;
    float flo = (mlo < 15.f) ? 66.6666667f * mlo : 1000.f * expf(LOGSTEP * (mlo - 15.f));
    float fhi = (mhi < 15.f) ? 66.6666667f * mhi : 1000.f * expf(LOGSTEP * (mhi - 15.f));
    int klo = (int)(flo * 0.064f) - 1;            // 1/15.625 = 0.064
    int khi = (int)(fhi * 0.064f) + 2;
    klo = max(klo, 0);
    khi = min(khi, NSTFT);
    return make_int2(klo, khi);
}

// One wave (64 lanes) per frame; 4 frames per 256-thread block.
// Packed-real 512-pt radix-8 Stockham FFT, in-place per-wave LDS buffer,
// no inter-wave barriers until the cross-wave output write.
__global__ __launch_bounds__(256) void melspec_kernel(
    const float* __restrict__ wav,     // [B][160000]
    const float* __restrict__ window,  // [1024]
    const float* __restrict__ fb,      // [513][80]
    const float* __restrict__ twr,     // cos(-2pi n/1024), n=0..1023
    const float* __restrict__ twi,     // sin(-2pi n/1024)
    float* __restrict__ out)           // [B][80][626]
{
    __shared__ float2 buf[4][BUFSZ];   // 18432 B, per-wave in-place FFT buffer
    __shared__ float  smag[4][SMAGSZ]; // 8256 B

    const int tid  = threadIdx.x;
    const int lane = tid & 63;
    const int w    = tid >> 6;
    const int b    = blockIdx.x / FBLKS;
    const int fblk = blockIdx.x % FBLKS;
    const int frame = fblk * 4 + w;
    const bool active = frame < NFRAMES;

    float2* Bf = buf[w];
    float*  sm = smag[w];
    float2 v[8];

    if (active) {
        // ---- load + window + fused stage 1 (Ns=1, no twiddles) ----
        const float* wb = wav + (size_t)b * WAVLEN;
        const int base = frame * HOP - 512;
        if (base >= 0 && base + NFFT <= WAVLEN) {
            #pragma unroll
            for (int r = 0; r < 8; ++r) {
                int n = lane + 64 * r;
                float2 s  = *(const float2*)(wb + base + 2 * n);
                float2 wn = *(const float2*)(window + 2 * n);
                v[r] = make_float2(s.x * wn.x, s.y * wn.y);
            }
        } else {
            #pragma unroll
            for (int r = 0; r < 8; ++r) {
                int n = lane + 64 * r;
                int g0 = base + 2 * n, g1 = g0 + 1;
                g0 = g0 < 0 ? -g0 : (g0 >= WAVLEN ? 2 * WAVLEN - 2 - g0 : g0);
                g1 = g1 < 0 ? -g1 : (g1 >= WAVLEN ? 2 * WAVLEN - 2 - g1 : g1);
                v[r] = make_float2(wb[g0] * window[2 * n], wb[g1] * window[2 * n + 1]);
            }
        }
        fft8(v);
        #pragma unroll
        for (int r = 0; r < 8; ++r) Bf[PAD(8 * lane + r)] = v[r];

        // ---- stage 2: Ns=8 (in-place: fft8 consumes all loads before stores) ----
        #pragma unroll
        for (int r = 0; r < 8; ++r) v[r] = Bf[PAD(lane + 64 * r)];
        const int jm = lane & 7;
        #pragma unroll
        for (int r = 1; r < 8; ++r) {
            int idx = 16 * r * jm;             // r*(j%8)/64 in 1/1024 units
            v[r] = cmul(v[r], make_float2(twr[idx], twi[idx]));
        }
        fft8(v);
        const int idxD = (lane >> 3) * 64 + jm;
        #pragma unroll
        for (int r = 0; r < 8; ++r) Bf[PAD(idxD + 8 * r)] = v[r];

        // ---- stage 3: Ns=64 (reads and writes the same per-lane slots) ----
        #pragma unroll
        for (int r = 0; r < 8; ++r) v[r] = Bf[PAD(lane + 64 * r)];
        #pragma unroll
        for (int r = 1; r < 8; ++r) {
            int idx = 2 * r * lane;            // r*(j%64)/512 in 1/1024 units
            v[r] = cmul(v[r], make_float2(twr[idx], twi[idx]));
        }
        fft8(v);
        #pragma unroll
        for (int r = 0; r < 8; ++r) Bf[PAD(lane + 64 * r)] = v[r];

        // ---- Hermitian unpack + magnitude into separate smag ----
        #pragma unroll
        for (int r = 0; r < 8; ++r) {
            int k = lane + 64 * r;
            if (k == 0) {
                float2 z0 = Bf[PAD(0)];
                sm[0]   = fabsf(z0.x + z0.y);
                sm[512] = fabsf(z0.x - z0.y);
            } else {
                float2 zk = Bf[PAD(k)];
                float2 zm = Bf[PAD(512 - k)];
                float xer = 0.5f * (zk.x + zm.x), xei = 0.5f * (zk.y - zm.y);
                float xod = 0.5f * (zk.y + zm.y), xoi = 0.5f * (zm.x - zk.x);
                float wr = twr[k], wi = twi[k];
                float xr = xer + fmaf(xod, wr, -xoi * wi);
                float xi = xei + fmaf(xod, wi,  xoi * wr);
                sm[k] = sqrtf(fmaf(xr, xr, xi * xi));
            }
        }

        // ---- sparse mel projection (analytic ranges); pmel overlays buf ----
        float* pmel = (float*)Bf;              // buf dead after unpack reads
        {
            int m = lane;
            int2 rr = mel_range(m);
            float acc = 0.f;
            for (int k = rr.x; k < rr.y; ++k)
                acc = fmaf(sm[k], fb[k * NMELS + m], acc);
            pmel[m] = acc;
            if (lane < 16) {
                m = lane + 64;
                rr = mel_range(m);
                acc = 0.f;
                for (int k = rr.x; k < rr.y; ++k)
                    acc = fmaf(sm[k], fb[k * NMELS + m], acc);
                pmel[m] = acc;
            }
        }
    }
    __syncthreads();   // single barrier: output reads pmel across waves

    // ---- coalesced output: thread pair writes float2 along frame dim ----
    if (tid < 160) {
        int m = tid >> 1, h = tid & 1;
        int f0 = fblk * 4 + 2 * h;
        if (f0 < NFRAMES) {
            float2 o;
            o.x = ((float*)buf[2 * h])[m];
            o.y = ((float*)buf[2 * h + 1])[m];
            *(float2*)(out + ((size_t)b * NMELS + m) * NFRAMES + f0) = o;
        }
    }
}

extern "C" void kernel_launch(void* const* d_in, const int* in_sizes, int n_in,
                              void* d_out, int out_size, void* d_ws, size_t ws_size,
                              hipStream_t stream) {
    const float* wav    = (const float*)d_in[0];
    const float* window = (const float*)d_in[1];
    const float* fb     = (const float*)d_in[2];
    const float* rfr    = (const float*)d_in[3];
    const float* rfi    = (const float*)d_in[4];
    float* out = (float*)d_out;

    int B = in_sizes[0] / WAVLEN;            // 32
    melspec_kernel<<<dim3(B * FBLKS), 256, 0, stream>>>(
        wav, window, fb, rfr + NFFT, rfi + NFFT, out);
}

// Round 8
// 117.974 us; speedup vs baseline: 3.4682x; 1.3567x over previous
//
#include <hip/hip_runtime.h>

#define WAVLEN   160000
#define NFRAMES  626
#define NFFT     1024
#define HOP      256
#define NSTFT    513
#define NMELS    80
#define FBLKS    157               // ceil(626/4)
#define PAD(i)   ((i) + ((i) >> 3))
#define BUFSZ    576               // PAD(511)=574 -> round up (float2)
#define PWSTRIDE 49                // max mel width ~41 + margin; odd -> bank rotation
#define PWTOT    (NMELS * PWSTRIDE)   // 3920 floats = 15680 B

__device__ __forceinline__ float2 cadd(float2 a, float2 b){ return make_float2(a.x+b.x, a.y+b.y); }
__device__ __forceinline__ float2 csub(float2 a, float2 b){ return make_float2(a.x-b.x, a.y-b.y); }
__device__ __forceinline__ float2 cmul(float2 a, float2 b){
    return make_float2(fmaf(a.x, b.x, -a.y*b.y), fmaf(a.x, b.y, a.y*b.x));
}
__device__ __forceinline__ float2 mulnegi(float2 a){ return make_float2(a.y, -a.x); } // a * (-i)

__device__ __forceinline__ void fft4(float2& a0, float2& a1, float2& a2, float2& a3) {
    float2 t0 = cadd(a0, a2), t1 = csub(a0, a2);
    float2 t2 = cadd(a1, a3), t3 = csub(a1, a3);
    a0 = cadd(t0, t2); a2 = csub(t0, t2);
    float2 nt3 = mulnegi(t3);
    a1 = cadd(t1, nt3); a3 = csub(t1, nt3);
}

// 8-point DFT, natural in / natural out, no external twiddles.
__device__ __forceinline__ void fft8(float2 v[8]) {
    float2 e0=v[0], e1=v[2], e2=v[4], e3=v[6];
    float2 o0=v[1], o1=v[3], o2=v[5], o3=v[7];
    fft4(e0,e1,e2,e3);
    fft4(o0,o1,o2,o3);
    const float C = 0.70710678118654752f;
    float2 w1o = make_float2(C*(o1.x + o1.y), C*(o1.y - o1.x));   // o1 * c(1-i)
    float2 w2o = mulnegi(o2);                                     // o2 * (-i)
    float2 w3o = make_float2(C*(o3.y - o3.x), -C*(o3.x + o3.y));  // o3 * c(-1-i)
    v[0] = cadd(e0, o0);  v[4] = csub(e0, o0);
    v[1] = cadd(e1, w1o); v[5] = csub(e1, w1o);
    v[2] = cadd(e2, w2o); v[6] = csub(e2, w2o);
    v[3] = cadd(e3, w3o); v[7] = csub(e3, w3o);
}

// Analytic Slaney mel-band support [klo, khi) with +/-1-bin margin.
// Extra bins multiply fb==0, so a conservative range is unconditionally correct.
// MUST be identical in prep and main kernels (deterministic -> same results).
__device__ __forceinline__ int2 mel_range(int m) {
    const float LOGSTEP = 0.06875177742094912f;   // ln(6.4)/27
    const float MSTEP   = 0.55858524f;            // (15 + ln(8)/LOGSTEP)/81
    float mlo = (float)m * MSTEP;
    float mhi = (float)(m + 2) * MSTEP;
    float flo = (mlo < 15.f) ? 66.6666667f * mlo : 1000.f * expf(LOGSTEP * (mlo - 15.f));
    float fhi = (mhi < 15.f) ? 66.6666667f * mhi : 1000.f * expf(LOGSTEP * (mhi - 15.f));
    int klo = (int)(flo * 0.064f) - 1;            // 1/15.625 = 0.064
    int khi = (int)(fhi * 0.064f) + 2;
    klo = max(klo, 0);
    khi = min(khi, NSTFT);
    return make_int2(klo, khi);
}

// Prep: pack each mel's nonzero fb column run into pwg[m*PWSTRIDE + j].
// Runs once per launch (~few us); removes per-frame 64-line fb gathers.
__global__ __launch_bounds__(1024) void mel_pack_kernel(const float* __restrict__ fb,
                                                        float* __restrict__ pwg) {
    int p = threadIdx.x;
    #pragma unroll
    for (int it = 0; it < 4; ++it, p += 1024) {
        if (p < PWTOT) {
            int m = p / PWSTRIDE, j = p - m * PWSTRIDE;
            int2 rr = mel_range(m);
            float val = 0.f;
            if (j < rr.y - rr.x) val = fb[(rr.x + j) * NMELS + m];
            pwg[p] = val;
        }
    }
}

// One wave (64 lanes) per frame; 4 frames per 256-thread block.
// Packed-real 512-pt radix-8 Stockham FFT, in-place per-wave LDS buffer,
// iterative-power twiddles (no gathered table loads), LDS-packed mel weights.
__global__ __launch_bounds__(256) void melspec_kernel(
    const float* __restrict__ wav,     // [B][160000]
    const float* __restrict__ window,  // [1024]
    const float* __restrict__ fb,      // [513][80] (fallback only)
    const float* __restrict__ twr,     // cos(-2pi n/1024), n=0..1023
    const float* __restrict__ twi,     // sin(-2pi n/1024)
    const float* __restrict__ pwg,     // [80*49] packed mel weights (may be null)
    float* __restrict__ out)           // [B][80][626]
{
    __shared__ float2 buf[4][BUFSZ];   // 18432 B per-wave FFT buffer (sm/pmel overlay)
    __shared__ float  pw[PWTOT];       // 15680 B packed mel weights -> 34112 B total

    const int tid  = threadIdx.x;
    const int lane = tid & 63;
    const int w    = tid >> 6;
    const int b    = blockIdx.x / FBLKS;
    const int fblk = blockIdx.x % FBLKS;
    const int frame = fblk * 4 + w;
    const bool active = frame < NFRAMES;

    // ---- stage packed mel weights into LDS (coalesced), barrier once ----
    if (pwg) {
        for (int p = tid; p < PWTOT; p += 256) pw[p] = pwg[p];
    }
    __syncthreads();

    float2* Bf = buf[w];
    float2 v[8];

    if (active) {
        // ---- load + window + fused stage 1 (Ns=1, no twiddles) ----
        const float* wb = wav + (size_t)b * WAVLEN;
        const int base = frame * HOP - 512;
        if (base >= 0 && base + NFFT <= WAVLEN) {
            #pragma unroll
            for (int r = 0; r < 8; ++r) {
                int n = lane + 64 * r;
                float2 s  = *(const float2*)(wb + base + 2 * n);
                float2 wn = *(const float2*)(window + 2 * n);
                v[r] = make_float2(s.x * wn.x, s.y * wn.y);
            }
        } else {
            #pragma unroll
            for (int r = 0; r < 8; ++r) {
                int n = lane + 64 * r;
                int g0 = base + 2 * n, g1 = g0 + 1;
                g0 = g0 < 0 ? -g0 : (g0 >= WAVLEN ? 2 * WAVLEN - 2 - g0 : g0);
                g1 = g1 < 0 ? -g1 : (g1 >= WAVLEN ? 2 * WAVLEN - 2 - g1 : g1);
                v[r] = make_float2(wb[g0] * window[2 * n], wb[g1] * window[2 * n + 1]);
            }
        }
        fft8(v);
        #pragma unroll
        for (int r = 0; r < 8; ++r) Bf[PAD(8 * lane + r)] = v[r];

        // ---- stage 2: Ns=8; twiddles = powers of one per-lane base ----
        #pragma unroll
        for (int r = 0; r < 8; ++r) v[r] = Bf[PAD(lane + 64 * r)];
        const int jm = lane & 7;
        {
            float2 b2 = make_float2(twr[16 * jm], twi[16 * jm]);
            float2 u = b2;
            v[1] = cmul(v[1], u);
            #pragma unroll
            for (int r = 2; r < 8; ++r) { u = cmul(u, b2); v[r] = cmul(v[r], u); }
        }
        fft8(v);
        const int idxD = (lane >> 3) * 64 + jm;
        #pragma unroll
        for (int r = 0; r < 8; ++r) Bf[PAD(idxD + 8 * r)] = v[r];

        // ---- stage 3: Ns=64; same iterative-power twiddles ----
        #pragma unroll
        for (int r = 0; r < 8; ++r) v[r] = Bf[PAD(lane + 64 * r)];
        {
            float2 b3 = make_float2(twr[2 * lane], twi[2 * lane]);
            float2 u = b3;
            v[1] = cmul(v[1], u);
            #pragma unroll
            for (int r = 2; r < 8; ++r) { u = cmul(u, b3); v[r] = cmul(v[r], u); }
        }
        fft8(v);
        #pragma unroll
        for (int r = 0; r < 8; ++r) Bf[PAD(lane + 64 * r)] = v[r];
        // note: v[r] still holds Z[lane+64r] -- reused below as zk.

        // ---- Hermitian unpack, register-staged (reads drain before sm writes) ----
        float2 zm[8]; float wrk[8], wik[8];
        #pragma unroll
        for (int r = 0; r < 8; ++r) {
            int k = lane + 64 * r;
            zm[r] = Bf[PAD((512 - k) & 511)];   // k==0 -> reads Z[0] (unused then)
            wrk[r] = twr[k]; wik[r] = twi[k];   // coalesced
        }
        float* sm = (float*)Bf + 96;            // overlay: floats 96..611 of buf[w]
        #pragma unroll
        for (int r = 0; r < 8; ++r) {
            int k = lane + 64 * r;
            if (k == 0) {
                sm[0]   = fabsf(v[0].x + v[0].y);
                sm[512] = fabsf(v[0].x - v[0].y);
            } else {
                float xer = 0.5f * (v[r].x + zm[r].x), xei = 0.5f * (v[r].y - zm[r].y);
                float xod = 0.5f * (v[r].y + zm[r].y), xoi = 0.5f * (zm[r].x - v[r].x);
                float xr = xer + fmaf(xod, wrk[r], -xoi * wik[r]);
                float xi = xei + fmaf(xod, wik[r],  xoi * wrk[r]);
                sm[k] = sqrtf(fmaf(xr, xr, xi * xi));
            }
        }

        // ---- sparse mel projection from LDS-packed weights ----
        float* pmel = (float*)Bf;               // floats 0..79 (disjoint from sm)
        if (pwg) {
            int m = lane;
            int2 rr = mel_range(m);
            int wd = rr.y - rr.x;
            float acc = 0.f;
            for (int j = 0; j < wd; ++j)
                acc = fmaf(sm[rr.x + j], pw[m * PWSTRIDE + j], acc);
            pmel[m] = acc;
            if (lane < 16) {
                m = lane + 64;
                rr = mel_range(m); wd = rr.y - rr.x;
                acc = 0.f;
                for (int j = 0; j < wd; ++j)
                    acc = fmaf(sm[rr.x + j], pw[m * PWSTRIDE + j], acc);
                pmel[m] = acc;
            }
        } else {                                // fallback: direct fb walk
            int m = lane;
            int2 rr = mel_range(m);
            float acc = 0.f;
            for (int k = rr.x; k < rr.y; ++k)
                acc = fmaf(sm[k], fb[k * NMELS + m], acc);
            pmel[m] = acc;
            if (lane < 16) {
                m = lane + 64;
                rr = mel_range(m);
                acc = 0.f;
                for (int k = rr.x; k < rr.y; ++k)
                    acc = fmaf(sm[k], fb[k * NMELS + m], acc);
                pmel[m] = acc;
            }
        }
    }
    __syncthreads();   // output reads pmel across waves

    // ---- coalesced output: thread pair writes float2 along frame dim ----
    if (tid < 160) {
        int m = tid >> 1, h = tid & 1;
        int f0 = fblk * 4 + 2 * h;
        if (f0 < NFRAMES) {
            float2 o;
            o.x = ((float*)buf[2 * h])[m];
            o.y = ((float*)buf[2 * h + 1])[m];
            *(float2*)(out + ((size_t)b * NMELS + m) * NFRAMES + f0) = o;
        }
    }
}

extern "C" void kernel_launch(void* const* d_in, const int* in_sizes, int n_in,
                              void* d_out, int out_size, void* d_ws, size_t ws_size,
                              hipStream_t stream) {
    const float* wav    = (const float*)d_in[0];
    const float* window = (const float*)d_in[1];
    const float* fb     = (const float*)d_in[2];
    const float* rfr    = (const float*)d_in[3];
    const float* rfi    = (const float*)d_in[4];
    float* out = (float*)d_out;

    float* pwg = nullptr;
    if (ws_size >= PWTOT * sizeof(float)) {
        pwg = (float*)d_ws;
        mel_pack_kernel<<<1, 1024, 0, stream>>>(fb, pwg);
    }

    int B = in_sizes[0] / WAVLEN;            // 32
    melspec_kernel<<<dim3(B * FBLKS), 256, 0, stream>>>(
        wav, window, fb, rfr + NFFT, rfi + NFFT, pwg, out);
}

// Round 10
// 109.659 us; speedup vs baseline: 3.7312x; 1.0758x over previous
//
#include <hip/hip_runtime.h>

#define WAVLEN   160000
#define NFRAMES  626
#define NFFT     1024
#define HOP      256
#define NSTFT    513
#define NMELS    80
#define WPB      8                 // waves (frames) per block
#define FBLKS    79                // ceil(626/8)
#define PAD(i)   ((i) + ((i) >> 3))
#define BUFSZ    576               // PAD(511)=574 -> round up (float2)
#define PWSTRIDE 49                // max mel width ~41 + margin; odd -> bank rotation
#define PWTOT    (NMELS * PWSTRIDE)   // 3920 floats = 15680 B

__device__ __forceinline__ float2 cadd(float2 a, float2 b){ return make_float2(a.x+b.x, a.y+b.y); }
__device__ __forceinline__ float2 csub(float2 a, float2 b){ return make_float2(a.x-b.x, a.y-b.y); }
__device__ __forceinline__ float2 cmul(float2 a, float2 b){
    return make_float2(fmaf(a.x, b.x, -a.y*b.y), fmaf(a.x, b.y, a.y*b.x));
}
__device__ __forceinline__ float2 mulnegi(float2 a){ return make_float2(a.y, -a.x); } // a * (-i)

__device__ __forceinline__ void fft4(float2& a0, float2& a1, float2& a2, float2& a3) {
    float2 t0 = cadd(a0, a2), t1 = csub(a0, a2);
    float2 t2 = cadd(a1, a3), t3 = csub(a1, a3);
    a0 = cadd(t0, t2); a2 = csub(t0, t2);
    float2 nt3 = mulnegi(t3);
    a1 = cadd(t1, nt3); a3 = csub(t1, nt3);
}

// 8-point DFT, natural in / natural out, no external twiddles.
__device__ __forceinline__ void fft8(float2 v[8]) {
    float2 e0=v[0], e1=v[2], e2=v[4], e3=v[6];
    float2 o0=v[1], o1=v[3], o2=v[5], o3=v[7];
    fft4(e0,e1,e2,e3);
    fft4(o0,o1,o2,o3);
    const float C = 0.70710678118654752f;
    float2 w1o = make_float2(C*(o1.x + o1.y), C*(o1.y - o1.x));   // o1 * c(1-i)
    float2 w2o = mulnegi(o2);                                     // o2 * (-i)
    float2 w3o = make_float2(C*(o3.y - o3.x), -C*(o3.x + o3.y));  // o3 * c(-1-i)
    v[0] = cadd(e0, o0);  v[4] = csub(e0, o0);
    v[1] = cadd(e1, w1o); v[5] = csub(e1, w1o);
    v[2] = cadd(e2, w2o); v[6] = csub(e2, w2o);
    v[3] = cadd(e3, w3o); v[7] = csub(e3, w3o);
}

// Apply w^r, r=1..7, to v[1..7] with a log-depth power tree (dep depth 3).
__device__ __forceinline__ void twiddle7(float2 v[8], float2 b) {
    float2 u2 = cmul(b, b);
    float2 u3 = cmul(u2, b);
    float2 u4 = cmul(u2, u2);
    float2 u5 = cmul(u4, b);
    float2 u6 = cmul(u4, u2);
    float2 u7 = cmul(u4, u3);
    v[1] = cmul(v[1], b);  v[2] = cmul(v[2], u2);
    v[3] = cmul(v[3], u3); v[4] = cmul(v[4], u4);
    v[5] = cmul(v[5], u5); v[6] = cmul(v[6], u6);
    v[7] = cmul(v[7], u7);
}

// Analytic Slaney mel-band support [klo, khi) with +/-1-bin margin.
// Extra bins multiply fb==0, so a conservative range is unconditionally correct.
// MUST be identical in prep and main kernels (deterministic -> same results).
__device__ __forceinline__ int2 mel_range(int m) {
    const float LOGSTEP = 0.06875177742094912f;   // ln(6.4)/27
    const float MSTEP   = 0.55858524f;            // (15 + ln(8)/LOGSTEP)/81
    float mlo = (float)m * MSTEP;
    float mhi = (float)(m + 2) * MSTEP;
    float flo = (mlo < 15.f) ? 66.6666667f * mlo : 1000.f * expf(LOGSTEP * (mlo - 15.f));
    float fhi = (mhi < 15.f) ? 66.6666667f * mhi : 1000.f * expf(LOGSTEP * (mhi - 15.f));
    int klo = (int)(flo * 0.064f) - 1;            // 1/15.625 = 0.064
    int khi = (int)(fhi * 0.064f) + 2;
    klo = max(klo, 0);
    khi = min(khi, NSTFT);
    return make_int2(klo, khi);
}

// Prep: pack each mel's nonzero fb column run into pwg[m*PWSTRIDE + j].
__global__ __launch_bounds__(1024) void mel_pack_kernel(const float* __restrict__ fb,
                                                        float* __restrict__ pwg) {
    int p = threadIdx.x;
    #pragma unroll
    for (int it = 0; it < 4; ++it, p += 1024) {
        if (p < PWTOT) {
            int m = p / PWSTRIDE, j = p - m * PWSTRIDE;
            int2 rr = mel_range(m);
            float val = 0.f;
            if (j < rr.y - rr.x) val = fb[(rr.x + j) * NMELS + m];
            pwg[p] = val;
        }
    }
}

// One wave (64 lanes) per frame; 8 frames per 512-thread block.
// Packed-real 512-pt radix-8 Stockham FFT, in-place per-wave LDS buffer,
// log-depth twiddle powers, LDS-packed mel weights (amortized over 8 frames).
__global__ __launch_bounds__(512) void melspec_kernel(
    const float* __restrict__ wav,     // [B][160000]
    const float* __restrict__ window,  // [1024]
    const float* __restrict__ fb,      // [513][80] (fallback only)
    const float* __restrict__ twr,     // cos(-2pi n/1024), n=0..1023
    const float* __restrict__ twi,     // sin(-2pi n/1024)
    const float* __restrict__ pwg,     // [80*49] packed mel weights (may be null)
    float* __restrict__ out)           // [B][80][626]
{
    __shared__ float2 buf[WPB][BUFSZ];  // 36864 B per-block FFT buffers (overlay)
    __shared__ float  pw[PWTOT];        // 15680 B -> 52544 B total, 3 blocks/CU

    const int tid  = threadIdx.x;
    const int lane = tid & 63;
    const int w    = tid >> 6;
    const int b    = blockIdx.x / FBLKS;
    const int fblk = blockIdx.x % FBLKS;
    const int frame = fblk * WPB + w;
    const bool active = frame < NFRAMES;

    // ---- stage packed mel weights into LDS (coalesced), barrier once ----
    if (pwg) {
        for (int p = tid; p < PWTOT; p += 512) pw[p] = pwg[p];
    }
    __syncthreads();

    float2* Bf = buf[w];
    float2 v[8];

    if (active) {
        // ---- load + window + fused stage 1 (Ns=1, no twiddles) ----
        const float* wb = wav + (size_t)b * WAVLEN;
        const int base = frame * HOP - 512;
        if (base >= 0 && base + NFFT <= WAVLEN) {
            #pragma unroll
            for (int r = 0; r < 8; ++r) {
                int n = lane + 64 * r;
                float2 s  = *(const float2*)(wb + base + 2 * n);
                float2 wn = *(const float2*)(window + 2 * n);
                v[r] = make_float2(s.x * wn.x, s.y * wn.y);
            }
        } else {
            #pragma unroll
            for (int r = 0; r < 8; ++r) {
                int n = lane + 64 * r;
                int g0 = base + 2 * n, g1 = g0 + 1;
                g0 = g0 < 0 ? -g0 : (g0 >= WAVLEN ? 2 * WAVLEN - 2 - g0 : g0);
                g1 = g1 < 0 ? -g1 : (g1 >= WAVLEN ? 2 * WAVLEN - 2 - g1 : g1);
                v[r] = make_float2(wb[g0] * window[2 * n], wb[g1] * window[2 * n + 1]);
            }
        }
        fft8(v);
        #pragma unroll
        for (int r = 0; r < 8; ++r) Bf[PAD(8 * lane + r)] = v[r];

        // ---- stage 2: Ns=8 ----
        #pragma unroll
        for (int r = 0; r < 8; ++r) v[r] = Bf[PAD(lane + 64 * r)];
        const int jm = lane & 7;
        twiddle7(v, make_float2(twr[16 * jm], twi[16 * jm]));
        fft8(v);
        const int idxD = (lane >> 3) * 64 + jm;
        #pragma unroll
        for (int r = 0; r < 8; ++r) Bf[PAD(idxD + 8 * r)] = v[r];

        // ---- stage 3: Ns=64 ----
        #pragma unroll
        for (int r = 0; r < 8; ++r) v[r] = Bf[PAD(lane + 64 * r)];
        twiddle7(v, make_float2(twr[2 * lane], twi[2 * lane]));
        fft8(v);
        #pragma unroll
        for (int r = 0; r < 8; ++r) Bf[PAD(lane + 64 * r)] = v[r];
        // v[r] still holds Z[lane+64r] -- reused below as zk.

        // ---- Hermitian unpack, register-staged (reads drain before sm writes) ----
        float2 zm[8]; float wrk[8], wik[8];
        #pragma unroll
        for (int r = 0; r < 8; ++r) {
            int k = lane + 64 * r;
            zm[r] = Bf[PAD((512 - k) & 511)];
            wrk[r] = twr[k]; wik[r] = twi[k];   // coalesced
        }
        float* sm = (float*)Bf + 96;            // overlay: floats 96..611 of buf[w]
        #pragma unroll
        for (int r = 0; r < 8; ++r) {
            int k = lane + 64 * r;
            if (k == 0) {
                sm[0]   = fabsf(v[0].x + v[0].y);
                sm[512] = fabsf(v[0].x - v[0].y);
            } else {
                float xer = 0.5f * (v[r].x + zm[r].x), xei = 0.5f * (v[r].y - zm[r].y);
                float xod = 0.5f * (v[r].y + zm[r].y), xoi = 0.5f * (zm[r].x - v[r].x);
                float xr = xer + fmaf(xod, wrk[r], -xoi * wik[r]);
                float xi = xei + fmaf(xod, wik[r],  xoi * wrk[r]);
                sm[k] = sqrtf(fmaf(xr, xr, xi * xi));
            }
        }

        // ---- sparse mel projection; wide mels (16..79) first with all lanes,
        //      narrow mels (0..15, width<=8) by lanes 0..15 second ----
        float* pmel = (float*)Bf;               // floats 0..79 (disjoint from sm)
        if (pwg) {
            int m = 16 + lane;
            int2 rr = mel_range(m);
            int wd = rr.y - rr.x;
            float acc = 0.f;
            for (int j = 0; j < wd; ++j)
                acc = fmaf(sm[rr.x + j], pw[m * PWSTRIDE + j], acc);
            pmel[m] = acc;
            if (lane < 16) {
                m = lane;
                rr = mel_range(m); wd = rr.y - rr.x;
                acc = 0.f;
                for (int j = 0; j < wd; ++j)
                    acc = fmaf(sm[rr.x + j], pw[m * PWSTRIDE + j], acc);
                pmel[m] = acc;
            }
        } else {                                // fallback: direct fb walk
            int m = 16 + lane;
            int2 rr = mel_range(m);
            float acc = 0.f;
            for (int k = rr.x; k < rr.y; ++k)
                acc = fmaf(sm[k], fb[k * NMELS + m], acc);
            pmel[m] = acc;
            if (lane < 16) {
                m = lane;
                rr = mel_range(m);
                acc = 0.f;
                for (int k = rr.x; k < rr.y; ++k)
                    acc = fmaf(sm[k], fb[k * NMELS + m], acc);
                pmel[m] = acc;
            }
        }
    }
    __syncthreads();   // output reads pmel across waves

    // ---- coalesced output: 320 threads write float2 along frame dim ----
    if (tid < 320) {
        int m = tid >> 2, part = tid & 3;
        int f0 = fblk * WPB + 2 * part;
        if (f0 < NFRAMES) {
            float2 o;
            o.x = ((float*)buf[2 * part])[m];
            o.y = ((float*)buf[2 * part + 1])[m];
            *(float2*)(out + ((size_t)b * NMELS + m) * NFRAMES + f0) = o;
        }
    }
}

extern "C" void kernel_launch(void* const* d_in, const int* in_sizes, int n_in,
                              void* d_out, int out_size, void* d_ws, size_t ws_size,
                              hipStream_t stream) {
    const float* wav    = (const float*)d_in[0];
    const float* window = (const float*)d_in[1];
    const float* fb     = (const float*)d_in[2];
    const float* rfr    = (const float*)d_in[3];
    const float* rfi    = (const float*)d_in[4];
    float* out = (float*)d_out;

    float* pwg = nullptr;
    if (ws_size >= PWTOT * sizeof(float)) {
        pwg = (float*)d_ws;
        mel_pack_kernel<<<1, 1024, 0, stream>>>(fb, pwg);
    }

    int B = in_sizes[0] / WAVLEN;            // 32
    melspec_kernel<<<dim3(B * FBLKS), 512, 0, stream>>>(
        wav, window, fb, rfr + NFFT, rfi + NFFT, pwg, out);
}